// Round 1
// baseline (879.591 us; speedup 1.0000x reference)
//
#include <hip/hip_runtime.h>

// Problem constants
#define DIMD 1024
#define NHEAD 16
#define CHD 64
#define BBATCH 2
#define NSEQ 2048
#define NTOK 4096      // B*N
#define KDIM 1024

typedef __attribute__((ext_vector_type(4))) float f32x4;
typedef __attribute__((ext_vector_type(8))) short bf16x8;

__device__ __forceinline__ unsigned short f2bf(float f){
  unsigned int u = __float_as_uint(f);
  u += 0x7fffu + ((u >> 16) & 1u);       // RTNE
  return (unsigned short)(u >> 16);
}
__device__ __forceinline__ float bf2f(unsigned short u){
  return __uint_as_float(((unsigned int)u) << 16);
}

__device__ __forceinline__ void gl2lds16(const void* g, void* l){
  __builtin_amdgcn_global_load_lds(
      (const __attribute__((address_space(1))) unsigned int*)g,
      (__attribute__((address_space(3))) unsigned int*)l, 16, 0, 0);
}

// ---------------- LayerNorm: x (4096 x 1024) fp32 -> xn bf16 ----------------
__global__ __launch_bounds__(256) void ln_kernel(const float* __restrict__ x,
    const float* __restrict__ lw, const float* __restrict__ lb,
    unsigned short* __restrict__ xn){
  int row = blockIdx.x;
  int t = threadIdx.x;
  const float4* xr = (const float4*)(x + (size_t)row * DIMD);
  float4 v = xr[t];
  float s  = v.x + v.y + v.z + v.w;
  float s2 = v.x*v.x + v.y*v.y + v.z*v.z + v.w*v.w;
#pragma unroll
  for (int m = 1; m < 64; m <<= 1){
    s  += __shfl_xor(s,  m, 64);
    s2 += __shfl_xor(s2, m, 64);
  }
  __shared__ float red[8];
  int wv = t >> 6;
  if ((t & 63) == 0){ red[wv] = s; red[wv + 4] = s2; }
  __syncthreads();
  s  = red[0] + red[1] + red[2] + red[3];
  s2 = red[4] + red[5] + red[6] + red[7];
  float mu  = s  * (1.0f / DIMD);
  float var = s2 * (1.0f / DIMD) - mu * mu;
  float rs  = rsqrtf(var + 1e-5f);
  float4 w  = ((const float4*)lw)[t];
  float4 bb = ((const float4*)lb)[t];
  ushort4 o;
  o.x = f2bf((v.x - mu) * rs * w.x + bb.x);
  o.y = f2bf((v.y - mu) * rs * w.y + bb.y);
  o.z = f2bf((v.z - mu) * rs * w.z + bb.z);
  o.w = f2bf((v.w - mu) * rs * w.w + bb.w);
  ((ushort4*)xn)[(size_t)row * 256 + t] = o;
}

// ------------- weight convert/pack: fp32 -> bf16 -------------
// Wpack rows 0..3071 = w_qkv, rows 3072..4095 = w_g ; Wo = w_o
__global__ __launch_bounds__(256) void convert_w(const float* __restrict__ wqkv,
    const float* __restrict__ wg, const float* __restrict__ wo,
    unsigned short* __restrict__ Wpack, unsigned short* __restrict__ Wo){
  int i = blockIdx.x * 256 + threadIdx.x;      // float4 index
  const int NQP   = 4096 * 1024 / 4;
  const int NQQKV = 3072 * 1024 / 4;
  float4 v; unsigned short* dst;
  if (i < NQP){
    const float* src = (i < NQQKV) ? (wqkv + (size_t)i * 4)
                                   : (wg + (size_t)(i - NQQKV) * 4);
    v = *(const float4*)src;
    dst = Wpack + (size_t)i * 4;
  } else {
    int j = i - NQP;
    v = ((const float4*)wo)[j];
    dst = Wo + (size_t)j * 4;
  }
  ushort4 o = { f2bf(v.x), f2bf(v.y), f2bf(v.z), f2bf(v.w) };
  *(ushort4*)dst = o;
}

// ------------- shared GEMM core: 128x128 tile, BK=32, bf16 MFMA 16x16x32 ----
// A [M][1024], Bm [Ncols][1024], both bf16 K-major.
__device__ __forceinline__ void gemm_stage(const unsigned short* __restrict__ A,
    const unsigned short* __restrict__ Bm, int m0, int n0, int kb, char* lds, int tid){
#pragma unroll
  for (int i = 0; i < 4; i++){
    int c  = i * 256 + tid;        // 0..1023 ; <512 A, >=512 B
    int cc = c & 511;
    int r  = cc >> 2, k4 = cc & 3;
    const unsigned short* src =
        ((c >> 9) ? (Bm + (size_t)(n0 + r) * KDIM) : (A + (size_t)(m0 + r) * KDIM))
        + kb + k4 * 8;
    gl2lds16(src, lds + c * 16);
  }
}

__device__ __forceinline__ void gemm_main(const unsigned short* __restrict__ A,
    const unsigned short* __restrict__ Bm, int m0, int n0, char* lds,
    f32x4 acc[4][4], int wm, int wn, int l16, int quad){
  int tid = threadIdx.x;
  gemm_stage(A, Bm, m0, n0, 0, lds, tid);
  for (int kt = 0; kt < 32; kt++){
    __syncthreads();
    if (kt + 1 < 32)
      gemm_stage(A, Bm, m0, n0, (kt + 1) * 32, lds + ((kt + 1) & 1) * 16384, tid);
    const char* Ab = lds + (kt & 1) * 16384;
    const char* Bb = Ab + 8192;
    bf16x8 af[4], bfr[4];
#pragma unroll
    for (int t2 = 0; t2 < 4; t2++){
      af[t2]  = *(const bf16x8*)(Ab + (wm + t2 * 16 + l16) * 64 + quad * 16);
      bfr[t2] = *(const bf16x8*)(Bb + (wn + t2 * 16 + l16) * 64 + quad * 16);
    }
#pragma unroll
    for (int mt = 0; mt < 4; mt++)
#pragma unroll
      for (int nt = 0; nt < 4; nt++)
        acc[mt][nt] = __builtin_amdgcn_mfma_f32_16x16x32_bf16(af[mt], bfr[nt], acc[mt][nt], 0, 0, 0);
  }
}

// ------------- GEMM 1: xn @ Wpack^T -> scatter Q,K,Vt + sigmoid gate -------------
__global__ __launch_bounds__(256) void gemm_qkvg(const unsigned short* __restrict__ xn,
    const unsigned short* __restrict__ Wpack, const float* __restrict__ bg,
    unsigned short* __restrict__ Q, unsigned short* __restrict__ Ko,
    unsigned short* __restrict__ Vt, unsigned short* __restrict__ g){
  __shared__ char lds[32768];
  int tid = threadIdx.x, lane = tid & 63, wave = tid >> 6;
  int l16 = lane & 15, quad = lane >> 4;
  int wm = (wave & 1) * 64, wn = (wave >> 1) * 64;
  int m0 = blockIdx.y * 128, n0 = blockIdx.x * 128;
  f32x4 acc[4][4];
#pragma unroll
  for (int i = 0; i < 4; i++)
#pragma unroll
    for (int j = 0; j < 4; j++) acc[i][j] = (f32x4){0.f, 0.f, 0.f, 0.f};
  gemm_main(xn, Wpack, m0, n0, lds, acc, wm, wn, l16, quad);
#pragma unroll
  for (int mt = 0; mt < 4; mt++){
#pragma unroll
    for (int nt = 0; nt < 4; nt++){
      int col = n0 + wn + nt * 16 + l16;
#pragma unroll
      for (int reg = 0; reg < 4; reg++){
        int row = m0 + wm + mt * 16 + quad * 4 + reg;  // token
        float val = acc[mt][nt][reg];
        int b = row >> 11, n = row & 2047;
        if (col < 3072){
          int h = col / 192;
          int r = col - h * 192;
          int bh = b * 16 + h;
          if (r < 64)
            Q[((size_t)bh * 2048 + n) * 64 + r] = f2bf(val * 0.125f);
          else if (r < 128)
            Ko[((size_t)bh * 2048 + n) * 64 + (r - 64)] = f2bf(val);
          else
            Vt[((size_t)bh * 64 + (r - 128)) * 2048 + n] = f2bf(val);
        } else {
          int d = col - 3072;
          float gv = 1.0f / (1.0f + __expf(-(val + bg[d])));
          g[(size_t)row * 1024 + d] = f2bf(gv);
        }
      }
    }
  }
}

// ------------- flash attention: 64 q-rows/block, 64-key tiles -------------
__device__ __forceinline__ void attn_stage(const unsigned short* __restrict__ Kbh,
    const unsigned short* __restrict__ Vtbh, int kb, char* Kdst, char* Vdst, int tid){
#pragma unroll
  for (int i = 0; i < 2; i++){
    int l = i * 256 + tid;               // 512 chunks of 16B
    int n = l >> 3, cc = (l & 7) ^ (n & 7);   // XOR swizzle @16B granularity
    gl2lds16(Kbh + (size_t)(kb + n) * 64 + cc * 8, Kdst + l * 16);
  }
#pragma unroll
  for (int i = 0; i < 2; i++){
    int l = i * 256 + tid;
    int c = l >> 3, cc = (l & 7) ^ (c & 7);
    gl2lds16(Vtbh + (size_t)c * 2048 + kb + cc * 8, Vdst + l * 16);
  }
}

__global__ __launch_bounds__(256) void attn_kernel(
    const unsigned short* __restrict__ Q, const unsigned short* __restrict__ Ko,
    const unsigned short* __restrict__ Vt, const float* __restrict__ bias,
    const int* __restrict__ mask, const unsigned short* __restrict__ g,
    unsigned short* __restrict__ yg){
  __shared__ char smem[40960];   // K dbuf 2x8K | V dbuf 2x8K | P 4x2K
  int tid = threadIdx.x, lane = tid & 63, wave = tid >> 6;
  int l16 = lane & 15, quad = lane >> 4;
  int qt = blockIdx.x, bh = blockIdx.y;
  int b = bh >> 4, h = bh & 15;

  const unsigned short* Qbh  = Q  + (size_t)bh * 2048 * 64;
  const unsigned short* Kbh  = Ko + (size_t)bh * 2048 * 64;
  const unsigned short* Vtbh = Vt + (size_t)bh * 64 * 2048;
  const float* biasw = bias + (size_t)bh * 2048 * 2048 + (size_t)(qt * 64 + wave * 16) * 2048;
  const int* maskb = mask + b * 2048;
  char* Pw = smem + 32768 + wave * 2048;

  bf16x8 qf[2];
  {
    const unsigned short* qrow = Qbh + (size_t)(qt * 64 + wave * 16 + l16) * 64;
    qf[0] = *(const bf16x8*)(qrow + quad * 8);
    qf[1] = *(const bf16x8*)(qrow + 32 + quad * 8);
  }

  f32x4 yacc[4];
#pragma unroll
  for (int ct = 0; ct < 4; ct++) yacc[ct] = (f32x4){0.f, 0.f, 0.f, 0.f};
  float m_run[4] = {-1e30f, -1e30f, -1e30f, -1e30f};
  float l_run[4] = {0.f, 0.f, 0.f, 0.f};

  attn_stage(Kbh, Vtbh, 0, smem, smem + 16384, tid);

  for (int kt = 0; kt < 32; kt++){
    __syncthreads();
    int kb = kt * 64;
    // bias + mask loads first (so waiting on them doesn't drain next staging)
    float brow[4][4]; int mk[4];
#pragma unroll
    for (int nt = 0; nt < 4; nt++){
      mk[nt] = maskb[kb + nt * 16 + l16];
#pragma unroll
      for (int reg = 0; reg < 4; reg++)
        brow[nt][reg] = biasw[(size_t)(quad * 4 + reg) * 2048 + kb + nt * 16 + l16];
    }
    if (kt + 1 < 32)
      attn_stage(Kbh, Vtbh, kb + 64, smem + ((kt + 1) & 1) * 8192,
                 smem + 16384 + ((kt + 1) & 1) * 8192, tid);
    const char* Kb_ = smem + (kt & 1) * 8192;
    const char* Vb_ = smem + 16384 + (kt & 1) * 8192;

    f32x4 s[4];
#pragma unroll
    for (int nt = 0; nt < 4; nt++) s[nt] = (f32x4){0.f, 0.f, 0.f, 0.f};
#pragma unroll
    for (int kk = 0; kk < 2; kk++)
#pragma unroll
      for (int nt = 0; nt < 4; nt++){
        int n = nt * 16 + l16;
        bf16x8 kf = *(const bf16x8*)(Kb_ + n * 128 + ((((kk << 2) + quad) ^ (n & 7)) << 4));
        s[nt] = __builtin_amdgcn_mfma_f32_16x16x32_bf16(qf[kk], kf, s[nt], 0, 0, 0);
      }
    // bias + mask
#pragma unroll
    for (int nt = 0; nt < 4; nt++){
      bool ok = (mk[nt] != 0);
#pragma unroll
      for (int reg = 0; reg < 4; reg++){
        float v = s[nt][reg] + brow[nt][reg];
        s[nt][reg] = ok ? v : -1e30f;
      }
    }
    // online softmax (rows = quad*4+reg; reduce across 16 lanes of the quad)
    float mt_[4];
#pragma unroll
    for (int reg = 0; reg < 4; reg++)
      mt_[reg] = fmaxf(fmaxf(s[0][reg], s[1][reg]), fmaxf(s[2][reg], s[3][reg]));
#pragma unroll
    for (int reg = 0; reg < 4; reg++)
#pragma unroll
      for (int off = 1; off < 16; off <<= 1)
        mt_[reg] = fmaxf(mt_[reg], __shfl_xor(mt_[reg], off, 64));
    float alpha[4], psum[4];
#pragma unroll
    for (int reg = 0; reg < 4; reg++){
      float mn = fmaxf(m_run[reg], mt_[reg]);
      alpha[reg] = __expf(m_run[reg] - mn);
      m_run[reg] = mn;
      psum[reg] = 0.f;
    }
#pragma unroll
    for (int nt = 0; nt < 4; nt++){
      int n = nt * 16 + l16;
#pragma unroll
      for (int reg = 0; reg < 4; reg++){
        float p = __expf(s[nt][reg] - m_run[reg]);
        psum[reg] += p;
        int r = quad * 4 + reg;
        *(unsigned short*)(Pw + r * 128 + (((n >> 3) ^ (r & 7)) << 4) + ((n & 7) << 1)) = f2bf(p);
      }
    }
#pragma unroll
    for (int reg = 0; reg < 4; reg++){
#pragma unroll
      for (int off = 1; off < 16; off <<= 1)
        psum[reg] += __shfl_xor(psum[reg], off, 64);
      l_run[reg] = l_run[reg] * alpha[reg] + psum[reg];
    }
#pragma unroll
    for (int ct = 0; ct < 4; ct++)
#pragma unroll
      for (int reg = 0; reg < 4; reg++)
        yacc[ct][reg] *= alpha[reg];
    asm volatile("s_waitcnt lgkmcnt(0)" ::: "memory");  // P writes visible to own wave
    // PV
#pragma unroll
    for (int kk = 0; kk < 2; kk++){
      bf16x8 pf = *(const bf16x8*)(Pw + l16 * 128 + ((((kk << 2) + quad) ^ (l16 & 7)) << 4));
#pragma unroll
      for (int ct = 0; ct < 4; ct++){
        int c = ct * 16 + l16;
        bf16x8 vf = *(const bf16x8*)(Vb_ + c * 128 + ((((kk << 2) + quad) ^ (c & 7)) << 4));
        yacc[ct] = __builtin_amdgcn_mfma_f32_16x16x32_bf16(pf, vf, yacc[ct], 0, 0, 0);
      }
    }
  }
  // epilogue: y/l * gate -> yg bf16 (token-major, d = h*64 + c)
  float inv[4];
#pragma unroll
  for (int reg = 0; reg < 4; reg++) inv[reg] = 1.0f / l_run[reg];
#pragma unroll
  for (int ct = 0; ct < 4; ct++){
    int d = h * 64 + ct * 16 + l16;
#pragma unroll
    for (int reg = 0; reg < 4; reg++){
      int token = b * 2048 + qt * 64 + wave * 16 + quad * 4 + reg;
      float gv = bf2f(g[(size_t)token * 1024 + d]);
      yg[(size_t)token * 1024 + d] = f2bf(yacc[ct][reg] * inv[reg] * gv);
    }
  }
}

// ------------- GEMM 2: yg @ Wo^T + b_o -> out fp32 -------------
__global__ __launch_bounds__(256) void gemm_out(const unsigned short* __restrict__ yg,
    const unsigned short* __restrict__ Wo, const float* __restrict__ bo,
    float* __restrict__ out){
  __shared__ char lds[32768];
  int tid = threadIdx.x, lane = tid & 63, wave = tid >> 6;
  int l16 = lane & 15, quad = lane >> 4;
  int wm = (wave & 1) * 64, wn = (wave >> 1) * 64;
  int m0 = blockIdx.y * 128, n0 = blockIdx.x * 128;
  f32x4 acc[4][4];
#pragma unroll
  for (int i = 0; i < 4; i++)
#pragma unroll
    for (int j = 0; j < 4; j++) acc[i][j] = (f32x4){0.f, 0.f, 0.f, 0.f};
  gemm_main(yg, Wo, m0, n0, lds, acc, wm, wn, l16, quad);
#pragma unroll
  for (int mt = 0; mt < 4; mt++){
#pragma unroll
    for (int nt = 0; nt < 4; nt++){
      int col = n0 + wn + nt * 16 + l16;
#pragma unroll
      for (int reg = 0; reg < 4; reg++){
        int row = m0 + wm + mt * 16 + quad * 4 + reg;
        out[(size_t)row * 1024 + col] = acc[mt][nt][reg] + bo[col];
      }
    }
  }
}

extern "C" void kernel_launch(void* const* d_in, const int* in_sizes, int n_in,
                              void* d_out, int out_size, void* d_ws, size_t ws_size,
                              hipStream_t stream){
  const float* x    = (const float*)d_in[0];
  const float* bias = (const float*)d_in[1];
  const int*   mask = (const int*)d_in[2];
  const float* lnw  = (const float*)d_in[3];
  const float* lnb  = (const float*)d_in[4];
  const float* wqkv = (const float*)d_in[5];
  const float* wo   = (const float*)d_in[6];
  const float* bo   = (const float*)d_in[7];
  const float* wg   = (const float*)d_in[8];
  const float* bg   = (const float*)d_in[9];
  float* out = (float*)d_out;

  char* ws = (char*)d_ws;
  unsigned short* xn    = (unsigned short*)(ws);                 // 8 MiB
  unsigned short* Wpack = (unsigned short*)(ws + (8u  << 20));   // 8 MiB
  unsigned short* Wob   = (unsigned short*)(ws + (16u << 20));   // 2 MiB
  unsigned short* Qb    = (unsigned short*)(ws + (18u << 20));   // 8 MiB
  unsigned short* Kb    = (unsigned short*)(ws + (26u << 20));   // 8 MiB
  unsigned short* Vtb   = (unsigned short*)(ws + (34u << 20));   // 8 MiB
  unsigned short* gb    = (unsigned short*)(ws + (42u << 20));   // 8 MiB
  unsigned short* ygb   = (unsigned short*)(ws + (50u << 20));   // 8 MiB  (58 MiB total)

  ln_kernel<<<dim3(4096), dim3(256), 0, stream>>>(x, lnw, lnb, xn);
  convert_w<<<dim3(5120), dim3(256), 0, stream>>>(wqkv, wg, wo, Wpack, Wob);
  gemm_qkvg<<<dim3(32, 32), dim3(256), 0, stream>>>(xn, Wpack, bg, Qb, Kb, Vtb, gb);
  attn_kernel<<<dim3(32, 32), dim3(256), 0, stream>>>(Qb, Kb, Vtb, bias, mask, gb, ygb);
  gemm_out<<<dim3(8, 32), dim3(256), 0, stream>>>(ygb, Wob, bo, out);
}

// Round 2
// 855.269 us; speedup vs baseline: 1.0284x; 1.0284x over previous
//
#include <hip/hip_runtime.h>

// Problem constants
#define DIMD 1024
#define NHEAD 16
#define CHD 64
#define BBATCH 2
#define NSEQ 2048
#define NTOK 4096      // B*N
#define KDIM 1024
#define LOG2E 1.4426950408889634f

typedef __attribute__((ext_vector_type(4))) float f32x4;
typedef __attribute__((ext_vector_type(8))) short bf16x8;

__device__ __forceinline__ unsigned short f2bf(float f){
  unsigned int u = __float_as_uint(f);
  u += 0x7fffu + ((u >> 16) & 1u);       // RTNE
  return (unsigned short)(u >> 16);
}
__device__ __forceinline__ float bf2f(unsigned short u){
  return __uint_as_float(((unsigned int)u) << 16);
}

__device__ __forceinline__ void gl2lds16(const void* g, void* l){
  __builtin_amdgcn_global_load_lds(
      (const __attribute__((address_space(1))) unsigned int*)g,
      (__attribute__((address_space(3))) unsigned int*)l, 16, 0, 0);
}

// DPP 16-lane reductions (VALU pipe, no ds_swizzle)
template<int CTRL>
__device__ __forceinline__ float dppmv(float x){
  return __int_as_float(__builtin_amdgcn_mov_dpp(__float_as_int(x), CTRL, 0xF, 0xF, true));
}
__device__ __forceinline__ float rmax16(float x){
  x = fmaxf(x, dppmv<0xB1>(x));    // quad_perm {1,0,3,2}
  x = fmaxf(x, dppmv<0x4E>(x));    // quad_perm {2,3,0,1}
  x = fmaxf(x, dppmv<0x141>(x));   // row_half_mirror
  x = fmaxf(x, dppmv<0x140>(x));   // row_mirror
  return x;
}
__device__ __forceinline__ float rsum16(float x){
  x += dppmv<0xB1>(x);
  x += dppmv<0x4E>(x);
  x += dppmv<0x141>(x);
  x += dppmv<0x140>(x);
  return x;
}

// ------------- fused LN (blocks 0..4095) + weight bf16 convert (4096..9215) -------------
__global__ __launch_bounds__(256) void pre_kernel(const float* __restrict__ x,
    const float* __restrict__ lw, const float* __restrict__ lb,
    const float* __restrict__ wqkv, const float* __restrict__ wg,
    const float* __restrict__ wo, unsigned short* __restrict__ xn,
    unsigned short* __restrict__ Wpack, unsigned short* __restrict__ Wo){
  __shared__ float red[8];
  int t = threadIdx.x;
  if (blockIdx.x < 4096){
    int row = blockIdx.x;
    const float4* xr = (const float4*)(x + (size_t)row * DIMD);
    float4 v = xr[t];
    float s  = v.x + v.y + v.z + v.w;
    float s2 = v.x*v.x + v.y*v.y + v.z*v.z + v.w*v.w;
#pragma unroll
    for (int m = 1; m < 64; m <<= 1){
      s  += __shfl_xor(s,  m, 64);
      s2 += __shfl_xor(s2, m, 64);
    }
    int wv = t >> 6;
    if ((t & 63) == 0){ red[wv] = s; red[wv + 4] = s2; }
    __syncthreads();
    s  = red[0] + red[1] + red[2] + red[3];
    s2 = red[4] + red[5] + red[6] + red[7];
    float mu  = s  * (1.0f / DIMD);
    float var = s2 * (1.0f / DIMD) - mu * mu;
    float rs  = rsqrtf(var + 1e-5f);
    float4 w  = ((const float4*)lw)[t];
    float4 bb = ((const float4*)lb)[t];
    ushort4 o;
    o.x = f2bf((v.x - mu) * rs * w.x + bb.x);
    o.y = f2bf((v.y - mu) * rs * w.y + bb.y);
    o.z = f2bf((v.z - mu) * rs * w.z + bb.z);
    o.w = f2bf((v.w - mu) * rs * w.w + bb.w);
    ((ushort4*)xn)[(size_t)row * 256 + t] = o;
  } else {
    int i = (blockIdx.x - 4096) * 256 + t;   // float4 index
    const int NQP   = 4096 * 1024 / 4;
    const int NQQKV = 3072 * 1024 / 4;
    float4 v; unsigned short* dst;
    if (i < NQP){
      const float* src = (i < NQQKV) ? (wqkv + (size_t)i * 4)
                                     : (wg + (size_t)(i - NQQKV) * 4);
      v = *(const float4*)src;
      dst = Wpack + (size_t)i * 4;
    } else {
      int j = i - NQP;
      v = ((const float4*)wo)[j];
      dst = Wo + (size_t)j * 4;
    }
    ushort4 o = { f2bf(v.x), f2bf(v.y), f2bf(v.z), f2bf(v.w) };
    *(ushort4*)dst = o;
  }
}

// ------------- shared GEMM core: 128x128 tile, BK=32, bf16 MFMA 16x16x32 ----
__device__ __forceinline__ void gemm_stage(const unsigned short* __restrict__ A,
    const unsigned short* __restrict__ Bm, int m0, int n0, int kb, char* lds, int tid){
#pragma unroll
  for (int i = 0; i < 4; i++){
    int c  = i * 256 + tid;        // 0..1023 ; <512 A, >=512 B
    int cc = c & 511;
    int r  = cc >> 2, k4 = cc & 3;
    const unsigned short* src =
        ((c >> 9) ? (Bm + (size_t)(n0 + r) * KDIM) : (A + (size_t)(m0 + r) * KDIM))
        + kb + k4 * 8;
    gl2lds16(src, lds + c * 16);
  }
}

__device__ __forceinline__ void gemm_main(const unsigned short* __restrict__ A,
    const unsigned short* __restrict__ Bm, int m0, int n0, char* lds,
    f32x4 acc[4][4], int wm, int wn, int l16, int quad){
  int tid = threadIdx.x;
  gemm_stage(A, Bm, m0, n0, 0, lds, tid);
  for (int kt = 0; kt < 32; kt++){
    __syncthreads();
    if (kt + 1 < 32)
      gemm_stage(A, Bm, m0, n0, (kt + 1) * 32, lds + ((kt + 1) & 1) * 16384, tid);
    const char* Ab = lds + (kt & 1) * 16384;
    const char* Bb = Ab + 8192;
    bf16x8 af[4], bfr[4];
#pragma unroll
    for (int t2 = 0; t2 < 4; t2++){
      af[t2]  = *(const bf16x8*)(Ab + (wm + t2 * 16 + l16) * 64 + quad * 16);
      bfr[t2] = *(const bf16x8*)(Bb + (wn + t2 * 16 + l16) * 64 + quad * 16);
    }
#pragma unroll
    for (int mt = 0; mt < 4; mt++)
#pragma unroll
      for (int nt = 0; nt < 4; nt++)
        acc[mt][nt] = __builtin_amdgcn_mfma_f32_16x16x32_bf16(af[mt], bfr[nt], acc[mt][nt], 0, 0, 0);
  }
}

// ------------- GEMM 1: xn @ Wpack^T -> scatter Q,K,Vt + sigmoid gate -------------
__global__ __launch_bounds__(256) void gemm_qkvg(const unsigned short* __restrict__ xn,
    const unsigned short* __restrict__ Wpack, const float* __restrict__ bg,
    unsigned short* __restrict__ Q, unsigned short* __restrict__ Ko,
    unsigned short* __restrict__ Vt, unsigned short* __restrict__ g){
  __shared__ char lds[32768];
  int tid = threadIdx.x, lane = tid & 63, wave = tid >> 6;
  int l16 = lane & 15, quad = lane >> 4;
  int wm = (wave & 1) * 64, wn = (wave >> 1) * 64;
  int m0 = blockIdx.y * 128, n0 = blockIdx.x * 128;
  f32x4 acc[4][4];
#pragma unroll
  for (int i = 0; i < 4; i++)
#pragma unroll
    for (int j = 0; j < 4; j++) acc[i][j] = (f32x4){0.f, 0.f, 0.f, 0.f};
  gemm_main(xn, Wpack, m0, n0, lds, acc, wm, wn, l16, quad);
  const float QSCALE = 0.125f * LOG2E;   // fold log2e for exp2-softmax
#pragma unroll
  for (int mt = 0; mt < 4; mt++){
#pragma unroll
    for (int nt = 0; nt < 4; nt++){
      int col = n0 + wn + nt * 16 + l16;
#pragma unroll
      for (int reg = 0; reg < 4; reg++){
        int row = m0 + wm + mt * 16 + quad * 4 + reg;  // token
        float val = acc[mt][nt][reg];
        int b = row >> 11, n = row & 2047;
        if (col < 3072){
          int h = col / 192;
          int r = col - h * 192;
          int bh = b * 16 + h;
          if (r < 64)
            Q[((size_t)bh * 2048 + n) * 64 + r] = f2bf(val * QSCALE);
          else if (r < 128)
            Ko[((size_t)bh * 2048 + n) * 64 + (r - 64)] = f2bf(val);
          else
            Vt[((size_t)bh * 64 + (r - 128)) * 2048 + n] = f2bf(val);
        } else {
          int d = col - 3072;
          float gv = 1.0f / (1.0f + __expf(-(val + bg[d])));
          g[(size_t)row * 1024 + d] = f2bf(gv);
        }
      }
    }
  }
}

// ------------- flash attention: 64 q-rows/block, 64-key tiles -------------
__device__ __forceinline__ void attn_stage(const unsigned short* __restrict__ Kbh,
    const unsigned short* __restrict__ Vtbh, int kb, char* Kdst, char* Vdst, int tid){
#pragma unroll
  for (int i = 0; i < 2; i++){
    int l = i * 256 + tid;               // 512 chunks of 16B
    int n = l >> 3, cc = (l & 7) ^ (n & 7);   // XOR swizzle @16B granularity
    gl2lds16(Kbh + (size_t)(kb + n) * 64 + cc * 8, Kdst + l * 16);
  }
#pragma unroll
  for (int i = 0; i < 2; i++){
    int l = i * 256 + tid;
    int c = l >> 3, cc = (l & 7) ^ (c & 7);
    gl2lds16(Vtbh + (size_t)c * 2048 + kb + cc * 8, Vdst + l * 16);
  }
}

__global__ __launch_bounds__(256) void attn_kernel(
    const unsigned short* __restrict__ Q, const unsigned short* __restrict__ Ko,
    const unsigned short* __restrict__ Vt, const float* __restrict__ bias,
    const int* __restrict__ mask, const unsigned short* __restrict__ g,
    unsigned short* __restrict__ yg){
  __shared__ char smem[40960];   // K dbuf 2x8K | V dbuf 2x8K | P 4x2K
  int tid = threadIdx.x, lane = tid & 63, wave = tid >> 6;
  int l16 = lane & 15, quad = lane >> 4;
  int qt = blockIdx.x, bh = blockIdx.y;
  int b = bh >> 4, h = bh & 15;

  const unsigned short* Qbh  = Q  + (size_t)bh * 2048 * 64;
  const unsigned short* Kbh  = Ko + (size_t)bh * 2048 * 64;
  const unsigned short* Vtbh = Vt + (size_t)bh * 64 * 2048;
  const float* biasw = bias + (size_t)bh * 2048 * 2048 + (size_t)(qt * 64 + wave * 16) * 2048;
  const int* maskb = mask + b * 2048;
  char* Pw = smem + 32768 + wave * 2048;

  bf16x8 qf[2];
  {
    const unsigned short* qrow = Qbh + (size_t)(qt * 64 + wave * 16 + l16) * 64;
    qf[0] = *(const bf16x8*)(qrow + quad * 8);
    qf[1] = *(const bf16x8*)(qrow + 32 + quad * 8);
  }

  f32x4 yacc[4];
#pragma unroll
  for (int ct = 0; ct < 4; ct++) yacc[ct] = (f32x4){0.f, 0.f, 0.f, 0.f};
  float m_run[4] = {-1e30f, -1e30f, -1e30f, -1e30f};
  float l_run[4] = {0.f, 0.f, 0.f, 0.f};

  // prologue: stage tile 0 + prefetch bias/mask tile 0 (raw loads only)
  float ba[4][4], bb[4][4];
  int mka[4], mkb[4];
  attn_stage(Kbh, Vtbh, 0, smem, smem + 16384, tid);
#pragma unroll
  for (int nt = 0; nt < 4; nt++){
    mka[nt] = maskb[nt * 16 + l16];
#pragma unroll
    for (int reg = 0; reg < 4; reg++)
      ba[nt][reg] = biasw[(size_t)(quad * 4 + reg) * 2048 + nt * 16 + l16];
  }

  auto body = [&](int kt, float (&cur)[4][4], int (&mcur)[4],
                  float (&nxt)[4][4], int (&mnxt)[4]){
    __syncthreads();
    int kb = kt * 64;
    if (kt + 1 < 32){
      attn_stage(Kbh, Vtbh, kb + 64, smem + (((kt + 1) & 1) << 13),
                 smem + 16384 + (((kt + 1) & 1) << 13), tid);
      // raw prefetch of next bias/mask tile (no arithmetic -> waitcnt lands next iter)
#pragma unroll
      for (int nt = 0; nt < 4; nt++){
        mnxt[nt] = maskb[kb + 64 + nt * 16 + l16];
#pragma unroll
        for (int reg = 0; reg < 4; reg++)
          nxt[nt][reg] = biasw[(size_t)(quad * 4 + reg) * 2048 + kb + 64 + nt * 16 + l16];
      }
    }
    const char* Kb_ = smem + ((kt & 1) << 13);
    const char* Vb_ = smem + 16384 + ((kt & 1) << 13);

    // QK^T (Q pre-scaled by 0.125*log2e)
    f32x4 s[4];
#pragma unroll
    for (int nt = 0; nt < 4; nt++) s[nt] = (f32x4){0.f, 0.f, 0.f, 0.f};
#pragma unroll
    for (int kk = 0; kk < 2; kk++)
#pragma unroll
      for (int nt = 0; nt < 4; nt++){
        int n = nt * 16 + l16;
        bf16x8 kf = *(const bf16x8*)(Kb_ + n * 128 + ((((kk << 2) + quad) ^ (n & 7)) << 4));
        s[nt] = __builtin_amdgcn_mfma_f32_16x16x32_bf16(qf[kk], kf, s[nt], 0, 0, 0);
      }
    // bias (log2 units) + mask
#pragma unroll
    for (int nt = 0; nt < 4; nt++){
      bool ok = (mcur[nt] != 0);
#pragma unroll
      for (int reg = 0; reg < 4; reg++){
        float v = fmaf(cur[nt][reg], LOG2E, s[nt][reg]);
        s[nt][reg] = ok ? v : -1e30f;
      }
    }
    // online softmax in log2 domain; DPP reductions over the 16 lanes
    float alpha[4], psum[4];
#pragma unroll
    for (int reg = 0; reg < 4; reg++){
      float m4 = fmaxf(fmaxf(s[0][reg], s[1][reg]), fmaxf(s[2][reg], s[3][reg]));
      m4 = rmax16(m4);
      float mn = fmaxf(m_run[reg], m4);
      alpha[reg] = __builtin_amdgcn_exp2f(m_run[reg] - mn);
      m_run[reg] = mn;
      psum[reg] = 0.f;
    }
#pragma unroll
    for (int nt = 0; nt < 4; nt++){
      int n = nt * 16 + l16;
#pragma unroll
      for (int reg = 0; reg < 4; reg++){
        float p = __builtin_amdgcn_exp2f(s[nt][reg] - m_run[reg]);
        psum[reg] += p;
        int r = quad * 4 + reg;
        unsigned int u = __float_as_uint(p) + 0x8000u;   // fast round
        *(unsigned short*)(Pw + r * 128 + (((n >> 3) ^ (r & 7)) << 4) + ((n & 7) << 1)) =
            (unsigned short)(u >> 16);
      }
    }
#pragma unroll
    for (int reg = 0; reg < 4; reg++){
      float ps = rsum16(psum[reg]);
      l_run[reg] = l_run[reg] * alpha[reg] + ps;
    }
#pragma unroll
    for (int ct = 0; ct < 4; ct++)
#pragma unroll
      for (int reg = 0; reg < 4; reg++)
        yacc[ct][reg] *= alpha[reg];
    asm volatile("s_waitcnt lgkmcnt(0)" ::: "memory");  // P writes visible to own wave
    // PV
#pragma unroll
    for (int kk = 0; kk < 2; kk++){
      bf16x8 pf = *(const bf16x8*)(Pw + l16 * 128 + ((((kk << 2) + quad) ^ (l16 & 7)) << 4));
#pragma unroll
      for (int ct = 0; ct < 4; ct++){
        int c = ct * 16 + l16;
        bf16x8 vf = *(const bf16x8*)(Vb_ + c * 128 + ((((kk << 2) + quad) ^ (c & 7)) << 4));
        yacc[ct] = __builtin_amdgcn_mfma_f32_16x16x32_bf16(pf, vf, yacc[ct], 0, 0, 0);
      }
    }
  };

#pragma unroll 1
  for (int kt2 = 0; kt2 < 16; kt2++){
    body(kt2 * 2,     ba, mka, bb, mkb);
    body(kt2 * 2 + 1, bb, mkb, ba, mka);
  }

  // epilogue: y/l * gate -> yg bf16 (token-major, d = h*64 + c)
  float inv[4];
#pragma unroll
  for (int reg = 0; reg < 4; reg++) inv[reg] = __builtin_amdgcn_rcpf(l_run[reg]);
#pragma unroll
  for (int ct = 0; ct < 4; ct++){
    int d = h * 64 + ct * 16 + l16;
#pragma unroll
    for (int reg = 0; reg < 4; reg++){
      int token = b * 2048 + qt * 64 + wave * 16 + quad * 4 + reg;
      float gv = bf2f(g[(size_t)token * 1024 + d]);
      yg[(size_t)token * 1024 + d] = f2bf(yacc[ct][reg] * inv[reg] * gv);
    }
  }
}

// ------------- GEMM 2: yg @ Wo^T + b_o -> out fp32 -------------
__global__ __launch_bounds__(256) void gemm_out(const unsigned short* __restrict__ yg,
    const unsigned short* __restrict__ Wo, const float* __restrict__ bo,
    float* __restrict__ out){
  __shared__ char lds[32768];
  int tid = threadIdx.x, lane = tid & 63, wave = tid >> 6;
  int l16 = lane & 15, quad = lane >> 4;
  int wm = (wave & 1) * 64, wn = (wave >> 1) * 64;
  int m0 = blockIdx.y * 128, n0 = blockIdx.x * 128;
  f32x4 acc[4][4];
#pragma unroll
  for (int i = 0; i < 4; i++)
#pragma unroll
    for (int j = 0; j < 4; j++) acc[i][j] = (f32x4){0.f, 0.f, 0.f, 0.f};
  gemm_main(yg, Wo, m0, n0, lds, acc, wm, wn, l16, quad);
#pragma unroll
  for (int mt = 0; mt < 4; mt++){
#pragma unroll
    for (int nt = 0; nt < 4; nt++){
      int col = n0 + wn + nt * 16 + l16;
#pragma unroll
      for (int reg = 0; reg < 4; reg++){
        int row = m0 + wm + mt * 16 + quad * 4 + reg;
        out[(size_t)row * 1024 + col] = acc[mt][nt][reg] + bo[col];
      }
    }
  }
}

extern "C" void kernel_launch(void* const* d_in, const int* in_sizes, int n_in,
                              void* d_out, int out_size, void* d_ws, size_t ws_size,
                              hipStream_t stream){
  const float* x    = (const float*)d_in[0];
  const float* bias = (const float*)d_in[1];
  const int*   mask = (const int*)d_in[2];
  const float* lnw  = (const float*)d_in[3];
  const float* lnb  = (const float*)d_in[4];
  const float* wqkv = (const float*)d_in[5];
  const float* wo   = (const float*)d_in[6];
  const float* bo   = (const float*)d_in[7];
  const float* wg   = (const float*)d_in[8];
  const float* bg   = (const float*)d_in[9];
  float* out = (float*)d_out;

  char* ws = (char*)d_ws;
  unsigned short* xn    = (unsigned short*)(ws);                 // 8 MiB
  unsigned short* Wpack = (unsigned short*)(ws + (8u  << 20));   // 8 MiB
  unsigned short* Wob   = (unsigned short*)(ws + (16u << 20));   // 2 MiB
  unsigned short* Qb    = (unsigned short*)(ws + (18u << 20));   // 8 MiB
  unsigned short* Kb    = (unsigned short*)(ws + (26u << 20));   // 8 MiB
  unsigned short* Vtb   = (unsigned short*)(ws + (34u << 20));   // 8 MiB
  unsigned short* gb    = (unsigned short*)(ws + (42u << 20));   // 8 MiB
  unsigned short* ygb   = (unsigned short*)(ws + (50u << 20));   // 8 MiB  (58 MiB total)

  pre_kernel<<<dim3(9216), dim3(256), 0, stream>>>(x, lnw, lnb, wqkv, wg, wo, xn, Wpack, Wob);
  gemm_qkvg<<<dim3(32, 32), dim3(256), 0, stream>>>(xn, Wpack, bg, Qb, Kb, Vtb, gb);
  attn_kernel<<<dim3(32, 32), dim3(256), 0, stream>>>(Qb, Kb, Vtb, bias, mask, gb, ygb);
  gemm_out<<<dim3(8, 32), dim3(256), 0, stream>>>(ygb, Wob, bo, out);
}

// Round 3
// 837.522 us; speedup vs baseline: 1.0502x; 1.0212x over previous
//
#include <hip/hip_runtime.h>

// Problem constants
#define DIMD 1024
#define NHEAD 16
#define CHD 64
#define BBATCH 2
#define NSEQ 2048
#define NTOK 4096      // B*N
#define KDIM 1024
#define LOG2E 1.4426950408889634f

typedef __attribute__((ext_vector_type(4))) float f32x4;
typedef __attribute__((ext_vector_type(8))) short bf16x8;

__device__ __forceinline__ unsigned short f2bf(float f){
  unsigned int u = __float_as_uint(f);
  u += 0x7fffu + ((u >> 16) & 1u);       // RTNE
  return (unsigned short)(u >> 16);
}
__device__ __forceinline__ float bf2f(unsigned short u){
  return __uint_as_float(((unsigned int)u) << 16);
}

__device__ __forceinline__ void gl2lds16(const void* g, void* l){
  __builtin_amdgcn_global_load_lds(
      (const __attribute__((address_space(1))) unsigned int*)g,
      (__attribute__((address_space(3))) unsigned int*)l, 16, 0, 0);
}

// DPP 16-lane reductions (VALU pipe, no ds_swizzle)
template<int CTRL>
__device__ __forceinline__ float dppmv(float x){
  return __int_as_float(__builtin_amdgcn_mov_dpp(__float_as_int(x), CTRL, 0xF, 0xF, true));
}
__device__ __forceinline__ float rmax16(float x){
  x = fmaxf(x, dppmv<0xB1>(x));    // quad_perm {1,0,3,2}
  x = fmaxf(x, dppmv<0x4E>(x));    // quad_perm {2,3,0,1}
  x = fmaxf(x, dppmv<0x141>(x));   // row_half_mirror
  x = fmaxf(x, dppmv<0x140>(x));   // row_mirror
  return x;
}
__device__ __forceinline__ float rsum16(float x){
  x += dppmv<0xB1>(x);
  x += dppmv<0x4E>(x);
  x += dppmv<0x141>(x);
  x += dppmv<0x140>(x);
  return x;
}

// ------------- fused LN (blocks 0..4095) + weight bf16 convert/permute -------------
// Wpack column classes (pre-permuted): [0,1024)=Q h*64+c, [1024,2048)=K, [2048,3072)=V, [3072,4096)=gate
__global__ __launch_bounds__(256) void pre_kernel(const float* __restrict__ x,
    const float* __restrict__ lw, const float* __restrict__ lb,
    const float* __restrict__ wqkv, const float* __restrict__ wg,
    const float* __restrict__ wo, unsigned short* __restrict__ xn,
    unsigned short* __restrict__ Wpack, unsigned short* __restrict__ Wo){
  __shared__ float red[8];
  int t = threadIdx.x;
  if (blockIdx.x < 4096){
    int row = blockIdx.x;
    const float4* xr = (const float4*)(x + (size_t)row * DIMD);
    float4 v = xr[t];
    float s  = v.x + v.y + v.z + v.w;
    float s2 = v.x*v.x + v.y*v.y + v.z*v.z + v.w*v.w;
#pragma unroll
    for (int m = 1; m < 64; m <<= 1){
      s  += __shfl_xor(s,  m, 64);
      s2 += __shfl_xor(s2, m, 64);
    }
    int wv = t >> 6;
    if ((t & 63) == 0){ red[wv] = s; red[wv + 4] = s2; }
    __syncthreads();
    s  = red[0] + red[1] + red[2] + red[3];
    s2 = red[4] + red[5] + red[6] + red[7];
    float mu  = s  * (1.0f / DIMD);
    float var = s2 * (1.0f / DIMD) - mu * mu;
    float rs  = rsqrtf(var + 1e-5f);
    float4 w  = ((const float4*)lw)[t];
    float4 bb = ((const float4*)lb)[t];
    ushort4 o;
    o.x = f2bf((v.x - mu) * rs * w.x + bb.x);
    o.y = f2bf((v.y - mu) * rs * w.y + bb.y);
    o.z = f2bf((v.z - mu) * rs * w.z + bb.z);
    o.w = f2bf((v.w - mu) * rs * w.w + bb.w);
    ((ushort4*)xn)[(size_t)row * 256 + t] = o;
  } else {
    int i = (blockIdx.x - 4096) * 256 + t;   // float4 index
    const int NQP   = 4096 * 1024 / 4;       // 1048576
    const int NQQKV = 3072 * 1024 / 4;       // 786432
    float4 v; unsigned short* dst;
    if (i < NQQKV){
      v = ((const float4*)wqkv)[i];
      int e = i >> 8, k4 = i & 255;          // source row (output col e), float4-within-row
      int h = e / 192, r = e - h * 192;      // head, residual
      int e2 = ((r >> 6) << 10) + (h << 6) + (r & 63);  // class*1024 + h*64 + c
      dst = Wpack + (size_t)e2 * 1024 + k4 * 4;
    } else if (i < NQP){
      int j = i - NQQKV;
      v = ((const float4*)wg)[j];
      dst = Wpack + (size_t)3072 * 1024 + (size_t)j * 4;
    } else {
      int j = i - NQP;
      v = ((const float4*)wo)[j];
      dst = Wo + (size_t)j * 4;
    }
    ushort4 o = { f2bf(v.x), f2bf(v.y), f2bf(v.z), f2bf(v.w) };
    *(ushort4*)dst = o;
  }
}

// ------------- shared GEMM core: 128x128 tile, BK=32, bf16 MFMA 16x16x32 ----
__device__ __forceinline__ void gemm_stage(const unsigned short* __restrict__ A,
    const unsigned short* __restrict__ Bm, int m0, int n0, int kb, char* lds, int tid){
#pragma unroll
  for (int i = 0; i < 4; i++){
    int c  = i * 256 + tid;        // 0..1023 ; <512 A, >=512 B
    int cc = c & 511;
    int r  = cc >> 2, k4 = cc & 3;
    const unsigned short* src =
        ((c >> 9) ? (Bm + (size_t)(n0 + r) * KDIM) : (A + (size_t)(m0 + r) * KDIM))
        + kb + k4 * 8;
    gl2lds16(src, lds + c * 16);
  }
}

__device__ __forceinline__ void gemm_main(const unsigned short* __restrict__ A,
    const unsigned short* __restrict__ Bm, int m0, int n0, int kt0, int ktn, char* lds,
    f32x4 acc[4][4], int wm, int wn, int l16, int quad){
  int tid = threadIdx.x;
  gemm_stage(A, Bm, m0, n0, kt0 * 32, lds, tid);
  for (int kt = 0; kt < ktn; kt++){
    __syncthreads();
    if (kt + 1 < ktn)
      gemm_stage(A, Bm, m0, n0, (kt0 + kt + 1) * 32, lds + ((kt + 1) & 1) * 16384, tid);
    const char* Ab = lds + (kt & 1) * 16384;
    const char* Bb = Ab + 8192;
    bf16x8 af[4], bfr[4];
#pragma unroll
    for (int t2 = 0; t2 < 4; t2++){
      af[t2]  = *(const bf16x8*)(Ab + (wm + t2 * 16 + l16) * 64 + quad * 16);
      bfr[t2] = *(const bf16x8*)(Bb + (wn + t2 * 16 + l16) * 64 + quad * 16);
    }
#pragma unroll
    for (int mt = 0; mt < 4; mt++)
#pragma unroll
      for (int nt = 0; nt < 4; nt++)
        acc[mt][nt] = __builtin_amdgcn_mfma_f32_16x16x32_bf16(af[mt], bfr[nt], acc[mt][nt], 0, 0, 0);
  }
}

// ------------- GEMM 1: xn @ Wpack^T -> Q,K,Vt,gate (class-major, wave-uniform) -------------
__global__ __launch_bounds__(256) void gemm_qkvg(const unsigned short* __restrict__ xn,
    const unsigned short* __restrict__ Wpack, const float* __restrict__ bg,
    unsigned short* __restrict__ Q, unsigned short* __restrict__ Ko,
    unsigned short* __restrict__ Vt, unsigned short* __restrict__ g){
  __shared__ char lds[32768];
  int tid = threadIdx.x, lane = tid & 63, wave = tid >> 6;
  int l16 = lane & 15, quad = lane >> 4;
  int wm = (wave & 1) * 64, wn = (wave >> 1) * 64;
  int m0 = blockIdx.y * 128, n0 = blockIdx.x * 128;
  f32x4 acc[4][4];
#pragma unroll
  for (int i = 0; i < 4; i++)
#pragma unroll
    for (int j = 0; j < 4; j++) acc[i][j] = (f32x4){0.f, 0.f, 0.f, 0.f};
  gemm_main(xn, Wpack, m0, n0, 0, 32, lds, acc, wm, wn, l16, quad);
  const float QSCALE = 0.125f * LOG2E;   // fold log2e for exp2-softmax
  int cls = n0 >> 10;                    // 0 Q, 1 K, 2 V, 3 gate — uniform per block
  if (cls == 2){
    // V transposed: Vt[(bh*64+c)*2048 + n], 4 regs contiguous in n -> ushort4
#pragma unroll
    for (int mt = 0; mt < 4; mt++){
      int row0 = m0 + wm + mt * 16 + quad * 4;
      int b = row0 >> 11, n = row0 & 2047;
#pragma unroll
      for (int nt = 0; nt < 4; nt++){
        int cc = (n0 + wn + nt * 16 + l16) & 1023;
        int h = cc >> 6, c = cc & 63;
        ushort4 o = { f2bf(acc[mt][nt][0]), f2bf(acc[mt][nt][1]),
                      f2bf(acc[mt][nt][2]), f2bf(acc[mt][nt][3]) };
        *(ushort4*)(Vt + ((size_t)((b * 16 + h) * 64 + c) * 2048 + n)) = o;
      }
    }
  } else if (cls == 3){
#pragma unroll
    for (int mt = 0; mt < 4; mt++){
#pragma unroll
      for (int nt = 0; nt < 4; nt++){
        int d = (n0 + wn + nt * 16 + l16) & 1023;
        float bgd = bg[d];
#pragma unroll
        for (int reg = 0; reg < 4; reg++){
          int token = m0 + wm + mt * 16 + quad * 4 + reg;
          float t2 = -(acc[mt][nt][reg] + bgd) * LOG2E;
          float gv = __builtin_amdgcn_rcpf(1.0f + __builtin_amdgcn_exp2f(t2));
          g[(size_t)token * 1024 + d] = f2bf(gv);
        }
      }
    }
  } else {
    unsigned short* dst = (cls == 0) ? Q : Ko;
    float sc = (cls == 0) ? QSCALE : 1.0f;
#pragma unroll
    for (int mt = 0; mt < 4; mt++){
      int row0 = m0 + wm + mt * 16 + quad * 4;
      int b = row0 >> 11, n = row0 & 2047;
#pragma unroll
      for (int nt = 0; nt < 4; nt++){
        int cc = (n0 + wn + nt * 16 + l16) & 1023;
        int h = cc >> 6, c = cc & 63;
        size_t base = ((size_t)(b * 16 + h) * 2048 + n) * 64 + c;
#pragma unroll
        for (int reg = 0; reg < 4; reg++)
          dst[base + (size_t)reg * 64] = f2bf(acc[mt][nt][reg] * sc);
      }
    }
  }
}

// ------------- flash attention: 64 q-rows/block, 64-key tiles -------------
__device__ __forceinline__ void attn_stage(const unsigned short* __restrict__ Kbh,
    const unsigned short* __restrict__ Vtbh, int kb, char* Kdst, char* Vdst, int tid){
#pragma unroll
  for (int i = 0; i < 2; i++){
    int l = i * 256 + tid;               // 512 chunks of 16B
    int n = l >> 3, cc = (l & 7) ^ (n & 7);   // XOR swizzle @16B granularity
    gl2lds16(Kbh + (size_t)(kb + n) * 64 + cc * 8, Kdst + l * 16);
  }
#pragma unroll
  for (int i = 0; i < 2; i++){
    int l = i * 256 + tid;
    int c = l >> 3, cc = (l & 7) ^ (c & 7);
    gl2lds16(Vtbh + (size_t)c * 2048 + kb + cc * 8, Vdst + l * 16);
  }
}

__global__ __launch_bounds__(256) void attn_kernel(
    const unsigned short* __restrict__ Q, const unsigned short* __restrict__ Ko,
    const unsigned short* __restrict__ Vt, const float* __restrict__ bias,
    const int* __restrict__ mask, const unsigned short* __restrict__ g,
    unsigned short* __restrict__ yg){
  __shared__ char smem[40960];   // K dbuf 2x8K | V dbuf 2x8K | P 4x2K
  int tid = threadIdx.x, lane = tid & 63, wave = tid >> 6;
  int l16 = lane & 15, quad = lane >> 4;
  int qt = blockIdx.x, bh = blockIdx.y;
  int b = bh >> 4, h = bh & 15;

  const unsigned short* Qbh  = Q  + (size_t)bh * 2048 * 64;
  const unsigned short* Kbh  = Ko + (size_t)bh * 2048 * 64;
  const unsigned short* Vtbh = Vt + (size_t)bh * 64 * 2048;
  const float* biasw = bias + (size_t)bh * 2048 * 2048 + (size_t)(qt * 64 + wave * 16) * 2048;
  const int* maskb = mask + b * 2048;
  char* Pw = smem + 32768 + wave * 2048;

  bf16x8 qf[2];
  {
    const unsigned short* qrow = Qbh + (size_t)(qt * 64 + wave * 16 + l16) * 64;
    qf[0] = *(const bf16x8*)(qrow + quad * 8);
    qf[1] = *(const bf16x8*)(qrow + 32 + quad * 8);
  }

  f32x4 yacc[4];
#pragma unroll
  for (int ct = 0; ct < 4; ct++) yacc[ct] = (f32x4){0.f, 0.f, 0.f, 0.f};
  float m_run[4] = {-1e30f, -1e30f, -1e30f, -1e30f};
  float l_run[4] = {0.f, 0.f, 0.f, 0.f};

  // prologue: stage tile 0 + prefetch bias/mask tile 0 (raw loads only)
  float ba[4][4], bb[4][4];
  int mka[4], mkb[4];
  attn_stage(Kbh, Vtbh, 0, smem, smem + 16384, tid);
#pragma unroll
  for (int nt = 0; nt < 4; nt++){
    mka[nt] = maskb[nt * 16 + l16];
#pragma unroll
    for (int reg = 0; reg < 4; reg++)
      ba[nt][reg] = biasw[(size_t)(quad * 4 + reg) * 2048 + nt * 16 + l16];
  }

  auto body = [&](int kt, float (&cur)[4][4], int (&mcur)[4],
                  float (&nxt)[4][4], int (&mnxt)[4]){
    __syncthreads();
    int kb = kt * 64;
    if (kt + 1 < 32){
      attn_stage(Kbh, Vtbh, kb + 64, smem + (((kt + 1) & 1) << 13),
                 smem + 16384 + (((kt + 1) & 1) << 13), tid);
      // raw prefetch of next bias/mask tile (no arithmetic -> waitcnt lands next iter)
#pragma unroll
      for (int nt = 0; nt < 4; nt++){
        mnxt[nt] = maskb[kb + 64 + nt * 16 + l16];
#pragma unroll
        for (int reg = 0; reg < 4; reg++)
          nxt[nt][reg] = biasw[(size_t)(quad * 4 + reg) * 2048 + kb + 64 + nt * 16 + l16];
      }
    }
    const char* Kb_ = smem + ((kt & 1) << 13);
    const char* Vb_ = smem + 16384 + ((kt & 1) << 13);

    // QK^T (Q pre-scaled by 0.125*log2e)
    f32x4 s[4];
#pragma unroll
    for (int nt = 0; nt < 4; nt++) s[nt] = (f32x4){0.f, 0.f, 0.f, 0.f};
#pragma unroll
    for (int kk = 0; kk < 2; kk++)
#pragma unroll
      for (int nt = 0; nt < 4; nt++){
        int n = nt * 16 + l16;
        bf16x8 kf = *(const bf16x8*)(Kb_ + n * 128 + ((((kk << 2) + quad) ^ (n & 7)) << 4));
        s[nt] = __builtin_amdgcn_mfma_f32_16x16x32_bf16(qf[kk], kf, s[nt], 0, 0, 0);
      }
    // bias (log2 units) + mask
#pragma unroll
    for (int nt = 0; nt < 4; nt++){
      bool ok = (mcur[nt] != 0);
#pragma unroll
      for (int reg = 0; reg < 4; reg++){
        float v = fmaf(cur[nt][reg], LOG2E, s[nt][reg]);
        s[nt][reg] = ok ? v : -1e30f;
      }
    }
    // online softmax in log2 domain; DPP reductions over the 16 lanes
    float alpha[4], psum[4];
#pragma unroll
    for (int reg = 0; reg < 4; reg++){
      float m4 = fmaxf(fmaxf(s[0][reg], s[1][reg]), fmaxf(s[2][reg], s[3][reg]));
      m4 = rmax16(m4);
      float mn = fmaxf(m_run[reg], m4);
      alpha[reg] = __builtin_amdgcn_exp2f(m_run[reg] - mn);
      m_run[reg] = mn;
      psum[reg] = 0.f;
    }
#pragma unroll
    for (int nt = 0; nt < 4; nt++){
      int n = nt * 16 + l16;
#pragma unroll
      for (int reg = 0; reg < 4; reg++){
        float p = __builtin_amdgcn_exp2f(s[nt][reg] - m_run[reg]);
        psum[reg] += p;
        int r = quad * 4 + reg;
        unsigned int u = __float_as_uint(p) + 0x8000u;   // fast round
        *(unsigned short*)(Pw + r * 128 + (((n >> 3) ^ (r & 7)) << 4) + ((n & 7) << 1)) =
            (unsigned short)(u >> 16);
      }
    }
#pragma unroll
    for (int reg = 0; reg < 4; reg++){
      float ps = rsum16(psum[reg]);
      l_run[reg] = l_run[reg] * alpha[reg] + ps;
    }
#pragma unroll
    for (int ct = 0; ct < 4; ct++)
#pragma unroll
      for (int reg = 0; reg < 4; reg++)
        yacc[ct][reg] *= alpha[reg];
    asm volatile("s_waitcnt lgkmcnt(0)" ::: "memory");  // P writes visible to own wave
    // PV
#pragma unroll
    for (int kk = 0; kk < 2; kk++){
      bf16x8 pf = *(const bf16x8*)(Pw + l16 * 128 + ((((kk << 2) + quad) ^ (l16 & 7)) << 4));
#pragma unroll
      for (int ct = 0; ct < 4; ct++){
        int c = ct * 16 + l16;
        bf16x8 vf = *(const bf16x8*)(Vb_ + c * 128 + ((((kk << 2) + quad) ^ (c & 7)) << 4));
        yacc[ct] = __builtin_amdgcn_mfma_f32_16x16x32_bf16(pf, vf, yacc[ct], 0, 0, 0);
      }
    }
  };

#pragma unroll 1
  for (int kt2 = 0; kt2 < 16; kt2++){
    body(kt2 * 2,     ba, mka, bb, mkb);
    body(kt2 * 2 + 1, bb, mkb, ba, mka);
  }

  // epilogue: y/l * gate -> yg bf16 (token-major, d = h*64 + c)
  float inv[4];
#pragma unroll
  for (int reg = 0; reg < 4; reg++) inv[reg] = __builtin_amdgcn_rcpf(l_run[reg]);
#pragma unroll
  for (int ct = 0; ct < 4; ct++){
    int d = h * 64 + ct * 16 + l16;
#pragma unroll
    for (int reg = 0; reg < 4; reg++){
      int token = b * 2048 + qt * 64 + wave * 16 + quad * 4 + reg;
      float gv = bf2f(g[(size_t)token * 1024 + d]);
      yg[(size_t)token * 1024 + d] = f2bf(yacc[ct][reg] * inv[reg] * gv);
    }
  }
}

// ------------- GEMM 2 (split-K x2): yg @ Wo^T -> fp32 partials -------------
__global__ __launch_bounds__(256) void gemm_out_sk(const unsigned short* __restrict__ yg,
    const unsigned short* __restrict__ Wo, float* __restrict__ part){
  __shared__ char lds[32768];
  int tid = threadIdx.x, lane = tid & 63, wave = tid >> 6;
  int l16 = lane & 15, quad = lane >> 4;
  int wm = (wave & 1) * 64, wn = (wave >> 1) * 64;
  int m0 = blockIdx.y * 128, n0 = blockIdx.x * 128;
  int z = blockIdx.z;
  f32x4 acc[4][4];
#pragma unroll
  for (int i = 0; i < 4; i++)
#pragma unroll
    for (int j = 0; j < 4; j++) acc[i][j] = (f32x4){0.f, 0.f, 0.f, 0.f};
  gemm_main(yg, Wo, m0, n0, z * 16, 16, lds, acc, wm, wn, l16, quad);
  float* pz = part + ((size_t)z << 22);   // 4096*1024 floats per half
#pragma unroll
  for (int mt = 0; mt < 4; mt++){
#pragma unroll
    for (int nt = 0; nt < 4; nt++){
      int col = n0 + wn + nt * 16 + l16;
#pragma unroll
      for (int reg = 0; reg < 4; reg++){
        int row = m0 + wm + mt * 16 + quad * 4 + reg;
        pz[(size_t)row * 1024 + col] = acc[mt][nt][reg];
      }
    }
  }
}

__global__ __launch_bounds__(256) void add_out(const float* __restrict__ part,
    const float* __restrict__ bo, float* __restrict__ out){
  int i = blockIdx.x * 256 + threadIdx.x;           // float4 index, 1048576 total
  float4 a = ((const float4*)part)[i];
  float4 b = ((const float4*)(part + (1u << 22)))[i];
  float4 c = ((const float4*)bo)[i & 255];
  float4 o = { a.x + b.x + c.x, a.y + b.y + c.y, a.z + b.z + c.z, a.w + b.w + c.w };
  ((float4*)out)[i] = o;
}

extern "C" void kernel_launch(void* const* d_in, const int* in_sizes, int n_in,
                              void* d_out, int out_size, void* d_ws, size_t ws_size,
                              hipStream_t stream){
  const float* x    = (const float*)d_in[0];
  const float* bias = (const float*)d_in[1];
  const int*   mask = (const int*)d_in[2];
  const float* lnw  = (const float*)d_in[3];
  const float* lnb  = (const float*)d_in[4];
  const float* wqkv = (const float*)d_in[5];
  const float* wo   = (const float*)d_in[6];
  const float* bo   = (const float*)d_in[7];
  const float* wg   = (const float*)d_in[8];
  const float* bg   = (const float*)d_in[9];
  float* out = (float*)d_out;

  char* ws = (char*)d_ws;
  unsigned short* xn    = (unsigned short*)(ws);                 // 8 MiB
  unsigned short* Wpack = (unsigned short*)(ws + (8u  << 20));   // 8 MiB
  unsigned short* Wob   = (unsigned short*)(ws + (16u << 20));   // 2 MiB
  unsigned short* Qb    = (unsigned short*)(ws + (18u << 20));   // 8 MiB
  unsigned short* Kb    = (unsigned short*)(ws + (26u << 20));   // 8 MiB
  unsigned short* Vtb   = (unsigned short*)(ws + (34u << 20));   // 8 MiB
  unsigned short* gb    = (unsigned short*)(ws + (42u << 20));   // 8 MiB
  unsigned short* ygb   = (unsigned short*)(ws + (50u << 20));   // 8 MiB
  float*          partb = (float*)(ws + (64u << 20));            // 32 MiB (96 total)

  pre_kernel<<<dim3(9216), dim3(256), 0, stream>>>(x, lnw, lnb, wqkv, wg, wo, xn, Wpack, Wob);
  gemm_qkvg<<<dim3(32, 32), dim3(256), 0, stream>>>(xn, Wpack, bg, Qb, Kb, Vtb, gb);
  attn_kernel<<<dim3(32, 32), dim3(256), 0, stream>>>(Qb, Kb, Vtb, bias, mask, gb, ygb);
  gemm_out_sk<<<dim3(8, 32, 2), dim3(256), 0, stream>>>(ygb, Wob, partb);
  add_out<<<dim3(4096), dim3(256), 0, stream>>>(partb, bo, out);
}